// Round 1
// baseline (3618.327 us; speedup 1.0000x reference)
//
#include <hip/hip_runtime.h>
#include <math.h>

// Problem constants
#define TT 2048      // T = B*S tokens
#define DD 2048      // D hidden
#define SS 1024      // S seq len
#define HH 16        // heads
#define NKV 4        // kv heads
#define HD 128       // head dim
#define NE 8         // experts
#define FF 2048      // ffn dim
#define OQ 3072      // qkv out dim (H+2*KV)*HD

// ---------------------------------------------------------------- LayerNorm
__global__ __launch_bounds__(256) void ln_kernel(const float* __restrict__ x,
                                                 const float* __restrict__ w,
                                                 float* __restrict__ out) {
    __shared__ float red[256];
    int row = blockIdx.x;
    int tid = threadIdx.x;
    const float* xr = x + (size_t)row * DD;
    float s = 0.f, s2 = 0.f;
    for (int d = tid; d < DD; d += 256) { float v = xr[d]; s += v; s2 = fmaf(v, v, s2); }
    red[tid] = s; __syncthreads();
    for (int off = 128; off > 0; off >>= 1) { if (tid < off) red[tid] += red[tid + off]; __syncthreads(); }
    float mean = red[0] / DD;
    __syncthreads();
    red[tid] = s2; __syncthreads();
    for (int off = 128; off > 0; off >>= 1) { if (tid < off) red[tid] += red[tid + off]; __syncthreads(); }
    float var = red[0] / DD - mean * mean;
    float rstd = rsqrtf(var + 1e-5f);
    for (int d = tid; d < DD; d += 256) {
        float v = xr[d];
        out[(size_t)row * DD + d] = (v - mean) * rstd * w[d];
    }
}

// ------------------------------------------------- fp32 GEMM, C = A * B^T (+add)
// A: M x K (row-major), B: N x K (row-major), C: M x N. Tiles 64x64, K-step 16.
__global__ __launch_bounds__(256) void gemm_nt(const float* __restrict__ A,
                                               const float* __restrict__ B,
                                               const float* __restrict__ add,
                                               float* __restrict__ C,
                                               int N, int K) {
    __shared__ float As[16][64];
    __shared__ float Bs[16][64];
    int tid = threadIdx.x;
    int m0 = blockIdx.y * 64, n0 = blockIdx.x * 64;
    int tm = tid >> 4, tn = tid & 15;
    int lr = tid >> 2;          // 0..63 row within tile for loads
    int lk = (tid & 3) << 2;    // k column group
    const float* Aload = A + (size_t)(m0 + lr) * K + lk;
    const float* Bload = B + (size_t)(n0 + lr) * K + lk;
    float acc[4][4] = {};
    for (int k0 = 0; k0 < K; k0 += 16) {
        float4 a4 = *(const float4*)(Aload + k0);
        float4 b4 = *(const float4*)(Bload + k0);
        __syncthreads();
        As[lk + 0][lr] = a4.x; As[lk + 1][lr] = a4.y; As[lk + 2][lr] = a4.z; As[lk + 3][lr] = a4.w;
        Bs[lk + 0][lr] = b4.x; Bs[lk + 1][lr] = b4.y; Bs[lk + 2][lr] = b4.z; Bs[lk + 3][lr] = b4.w;
        __syncthreads();
#pragma unroll
        for (int kk = 0; kk < 16; kk++) {
            float4 av = *(const float4*)(&As[kk][tm << 2]);
            float4 bv = *(const float4*)(&Bs[kk][tn << 2]);
            float a[4] = {av.x, av.y, av.z, av.w};
            float b[4] = {bv.x, bv.y, bv.z, bv.w};
#pragma unroll
            for (int i = 0; i < 4; i++)
#pragma unroll
                for (int j = 0; j < 4; j++) acc[i][j] = fmaf(a[i], b[j], acc[i][j]);
        }
    }
#pragma unroll
    for (int i = 0; i < 4; i++) {
        int m = m0 + (tm << 2) + i;
        float4 r = make_float4(acc[i][0], acc[i][1], acc[i][2], acc[i][3]);
        size_t idx = (size_t)m * N + n0 + (tn << 2);
        if (add) {
            float4 ad = *(const float4*)(add + idx);
            r.x += ad.x; r.y += ad.y; r.z += ad.z; r.w += ad.w;
        }
        *(float4*)(C + idx) = r;
    }
}

// ---------------------------------------------------------------- RoPE (q + k)
__global__ __launch_bounds__(256) void rope_kernel(float* __restrict__ qkv,
                                                   const float* __restrict__ cosb,
                                                   const float* __restrict__ sinb) {
    int idx = blockIdx.x * 256 + threadIdx.x;   // T * 20 heads * 64 pairs
    if (idx >= TT * 20 * 64) return;
    int d = idx & 63;
    int tmp = idx >> 6;
    int head = tmp % 20;    // 0..15 q heads, 16..19 k heads (contiguous at head*128)
    int t = tmp / 20;
    int s = t & (SS - 1);
    float c0 = cosb[s * HD + d], c1 = cosb[s * HD + d + 64];
    float s0 = sinb[s * HD + d], s1 = sinb[s * HD + d + 64];
    float* base = qkv + (size_t)t * OQ + head * HD;
    float x1 = base[d], x2 = base[d + 64];
    base[d]      = x1 * c0 - x2 * s0;
    base[d + 64] = x2 * c1 + x1 * s1;
}

// ------------------------------------------- causal GQA attention, online softmax
__global__ __launch_bounds__(128) void attn_kernel(const float* __restrict__ qkv,
                                                   float* __restrict__ attnout) {
    int qi = blockIdx.x, hh = blockIdx.y, b = blockIdx.z;
    int t = b * SS + qi;
    int kvh = hh >> 2;   // H/KV = 4
    int tid = threadIdx.x;
    __shared__ float qs[128], ps[128], red[128];
    qs[tid] = qkv[(size_t)t * OQ + hh * HD + tid];
    __syncthreads();
    float m = -1e30f, l = 0.f, o = 0.f;
    const float scale = 0.08838834764831845f;  // 1/sqrt(128)
    for (int k0 = 0; k0 <= qi; k0 += 128) {
        int nk = min(128, qi + 1 - k0);
        float sc = -1e30f;
        if (tid < nk) {
            const float* kr = qkv + (size_t)(b * SS + k0 + tid) * OQ + 2048 + kvh * HD;
            float acc = 0.f;
            for (int d = 0; d < HD; d++) acc = fmaf(qs[d], kr[d], acc);
            sc = acc * scale;
        }
        red[tid] = sc; __syncthreads();
        for (int off = 64; off > 0; off >>= 1) { if (tid < off) red[tid] = fmaxf(red[tid], red[tid + off]); __syncthreads(); }
        float mc = red[0]; __syncthreads();
        float mnew = fmaxf(m, mc);
        float pv = (tid < nk) ? expf(sc - mnew) : 0.f;
        ps[tid] = pv; red[tid] = pv; __syncthreads();
        for (int off = 64; off > 0; off >>= 1) { if (tid < off) red[tid] += red[tid + off]; __syncthreads(); }
        float psum = red[0];
        float alpha = expf(m - mnew);
        l = l * alpha + psum;
        o *= alpha;
        const float* vb = qkv + (size_t)(b * SS + k0) * OQ + 2560 + kvh * HD + tid;
        for (int j = 0; j < nk; j++) o = fmaf(ps[j], vb[(size_t)j * OQ], o);
        m = mnew;
        __syncthreads();
    }
    attnout[(size_t)t * DD + hh * HD + tid] = o / l;
}

// ---------------------------------------------------------------- Router
__global__ __launch_bounds__(256) void router_kernel(const float* __restrict__ x,
                                                     const float* __restrict__ wr,
                                                     int* __restrict__ tok_e,
                                                     float* __restrict__ tok_w,
                                                     int* __restrict__ counts) {
    __shared__ float red[256];
    __shared__ float logits[NE];
    int t = blockIdx.x;
    int tid = threadIdx.x;
    const float* xr = x + (size_t)t * DD;
    float acc[NE] = {};
    for (int d = tid; d < DD; d += 256) {
        float xv = xr[d];
#pragma unroll
        for (int e = 0; e < NE; e++) acc[e] = fmaf(xv, wr[e * DD + d], acc[e]);
    }
    for (int e = 0; e < NE; e++) {
        red[tid] = acc[e]; __syncthreads();
        for (int off = 128; off > 0; off >>= 1) { if (tid < off) red[tid] += red[tid + off]; __syncthreads(); }
        if (tid == 0) logits[e] = red[0];
        __syncthreads();
    }
    if (tid == 0) {
        float mx = logits[0];
        for (int e = 1; e < NE; e++) mx = fmaxf(mx, logits[e]);
        float ex[NE];
        for (int e = 0; e < NE; e++) ex[e] = expf(logits[e] - mx);
        int e0 = 0;
        for (int e = 1; e < NE; e++) if (ex[e] > ex[e0]) e0 = e;
        int e1 = -1;
        for (int e = 0; e < NE; e++) if (e != e0 && (e1 < 0 || ex[e] > ex[e1])) e1 = e;
        float w0 = ex[e0], w1 = ex[e1];
        float sw = w0 + w1;
        w0 /= sw; w1 /= sw;
        tok_e[2 * t] = e0; tok_e[2 * t + 1] = e1;
        tok_w[2 * t] = w0; tok_w[2 * t + 1] = w1;
        atomicAdd(&counts[e0], 1);
        atomicAdd(&counts[e1], 1);
    }
}

__global__ void offsets_kernel(const int* __restrict__ counts, int* __restrict__ offsets) {
    if (threadIdx.x == 0 && blockIdx.x == 0) {
        int acc = 0;
        for (int e = 0; e < NE; e++) { offsets[e] = acc; acc += counts[e]; }
    }
}

__global__ __launch_bounds__(256) void assign_kernel(const int* __restrict__ tok_e,
                                                     const float* __restrict__ tok_w,
                                                     const int* __restrict__ offsets,
                                                     int* __restrict__ cursors,
                                                     int* __restrict__ rowtok,
                                                     float* __restrict__ roww,
                                                     int* __restrict__ slotrow) {
    int t = blockIdx.x * 256 + threadIdx.x;
    if (t >= TT) return;
    for (int k = 0; k < 2; k++) {
        int e = tok_e[2 * t + k];
        int pos = atomicAdd(&cursors[e], 1);
        int row = offsets[e] + pos;
        rowtok[row] = t;
        roww[row] = tok_w[2 * t + k];
        slotrow[2 * t + k] = row;
    }
}

// ----------------------------- MoE gate+up fused GEMM (NN), gathered A rows
__global__ __launch_bounds__(256) void moe_gateup(const float* __restrict__ X,
                                                  const float* __restrict__ Wg,
                                                  const float* __restrict__ Wu,
                                                  float* __restrict__ P,
                                                  const int* __restrict__ rowtok,
                                                  const int* __restrict__ offsets,
                                                  const int* __restrict__ counts) {
    int e = blockIdx.z;
    int cnt = counts[e];
    int m0 = blockIdx.y * 64;
    if (m0 >= cnt) return;
    int n0 = blockIdx.x * 64;
    int off = offsets[e];
    __shared__ float As[16][64];
    __shared__ float Bg[16][64];
    __shared__ float Bu[16][64];
    __shared__ int rowt[64];
    int tid = threadIdx.x;
    if (tid < 64) {
        int m = m0 + tid;
        rowt[tid] = (m < cnt) ? rowtok[off + m] : -1;
    }
    __syncthreads();
    int lr = tid >> 2, lk = (tid & 3) << 2;       // A staging
    int bkr = tid >> 4, bnc = (tid & 15) << 2;    // B staging
    int arow = rowt[lr];
    const float* wg = Wg + (size_t)e * DD * FF;
    const float* wu = Wu + (size_t)e * DD * FF;
    float accg[4][4] = {}, accu[4][4] = {};
    int tm = tid >> 4, tn = tid & 15;
    for (int k0 = 0; k0 < DD; k0 += 16) {
        float4 a4 = make_float4(0.f, 0.f, 0.f, 0.f);
        if (arow >= 0) a4 = *(const float4*)(X + (size_t)arow * DD + k0 + lk);
        float4 g4 = *(const float4*)(wg + (size_t)(k0 + bkr) * FF + n0 + bnc);
        float4 u4 = *(const float4*)(wu + (size_t)(k0 + bkr) * FF + n0 + bnc);
        __syncthreads();
        As[lk + 0][lr] = a4.x; As[lk + 1][lr] = a4.y; As[lk + 2][lr] = a4.z; As[lk + 3][lr] = a4.w;
        *(float4*)&Bg[bkr][bnc] = g4;
        *(float4*)&Bu[bkr][bnc] = u4;
        __syncthreads();
#pragma unroll
        for (int kk = 0; kk < 16; kk++) {
            float4 av = *(const float4*)(&As[kk][tm << 2]);
            float4 gv = *(const float4*)(&Bg[kk][tn << 2]);
            float4 uv = *(const float4*)(&Bu[kk][tn << 2]);
            float a[4] = {av.x, av.y, av.z, av.w};
            float g[4] = {gv.x, gv.y, gv.z, gv.w};
            float u[4] = {uv.x, uv.y, uv.z, uv.w};
#pragma unroll
            for (int i = 0; i < 4; i++)
#pragma unroll
                for (int j = 0; j < 4; j++) {
                    accg[i][j] = fmaf(a[i], g[j], accg[i][j]);
                    accu[i][j] = fmaf(a[i], u[j], accu[i][j]);
                }
        }
    }
#pragma unroll
    for (int i = 0; i < 4; i++) {
        int m = m0 + (tm << 2) + i;
        if (m < cnt) {
            float4 r;
            float* rp = &r.x;
#pragma unroll
            for (int j = 0; j < 4; j++) {
                float g = accg[i][j], u = accu[i][j];
                rp[j] = (g / (1.f + expf(-g))) * u;   // silu(g)*u
            }
            *(float4*)(P + (size_t)(off + m) * FF + n0 + (tn << 2)) = r;
        }
    }
}

// ----------------------------- MoE down GEMM (NN), contiguous A rows
__global__ __launch_bounds__(256) void moe_down(const float* __restrict__ P,
                                                const float* __restrict__ Wd,
                                                float* __restrict__ Y,
                                                const int* __restrict__ offsets,
                                                const int* __restrict__ counts) {
    int e = blockIdx.z;
    int cnt = counts[e];
    int m0 = blockIdx.y * 64;
    if (m0 >= cnt) return;
    int n0 = blockIdx.x * 64;
    int off = offsets[e];
    __shared__ float As[16][64];
    __shared__ float Bs[16][64];
    int tid = threadIdx.x;
    int lr = tid >> 2, lk = (tid & 3) << 2;
    int bkr = tid >> 4, bnc = (tid & 15) << 2;
    const float* wd = Wd + (size_t)e * FF * DD;
    const float* aload = P + (size_t)(off + m0 + lr) * FF + lk;
    float acc[4][4] = {};
    int tm = tid >> 4, tn = tid & 15;
    for (int k0 = 0; k0 < FF; k0 += 16) {
        float4 a4 = *(const float4*)(aload + k0);
        float4 b4 = *(const float4*)(wd + (size_t)(k0 + bkr) * DD + n0 + bnc);
        __syncthreads();
        As[lk + 0][lr] = a4.x; As[lk + 1][lr] = a4.y; As[lk + 2][lr] = a4.z; As[lk + 3][lr] = a4.w;
        *(float4*)&Bs[bkr][bnc] = b4;
        __syncthreads();
#pragma unroll
        for (int kk = 0; kk < 16; kk++) {
            float4 av = *(const float4*)(&As[kk][tm << 2]);
            float4 bv = *(const float4*)(&Bs[kk][tn << 2]);
            float a[4] = {av.x, av.y, av.z, av.w};
            float b[4] = {bv.x, bv.y, bv.z, bv.w};
#pragma unroll
            for (int i = 0; i < 4; i++)
#pragma unroll
                for (int j = 0; j < 4; j++) acc[i][j] = fmaf(a[i], b[j], acc[i][j]);
        }
    }
#pragma unroll
    for (int i = 0; i < 4; i++) {
        int m = m0 + (tm << 2) + i;
        if (m < cnt) {
            float4 r = make_float4(acc[i][0], acc[i][1], acc[i][2], acc[i][3]);
            *(float4*)(Y + (size_t)(off + m) * DD + n0 + (tn << 2)) = r;
        }
    }
}

// ---------------------------------------------------------------- combine
__global__ __launch_bounds__(256) void combine_kernel(const float* __restrict__ Y,
                                                      const int* __restrict__ slotrow,
                                                      const float* __restrict__ roww,
                                                      float* __restrict__ out) {
    int i = blockIdx.x * 256 + threadIdx.x;   // T * (D/4)
    if (i >= TT * (DD / 4)) return;
    int t = i >> 9;        // D/4 = 512
    int d4 = i & 511;
    int r0 = slotrow[2 * t], r1 = slotrow[2 * t + 1];
    float w0 = roww[r0], w1 = roww[r1];
    float4 y0 = ((const float4*)Y)[(size_t)r0 * 512 + d4];
    float4 y1 = ((const float4*)Y)[(size_t)r1 * 512 + d4];
    float4 r;
    r.x = w0 * y0.x + w1 * y1.x;
    r.y = w0 * y0.y + w1 * y1.y;
    r.z = w0 * y0.z + w1 * y1.z;
    r.w = w0 * y0.w + w1 * y1.w;
    ((float4*)out)[i] = r;
}

// ---------------------------------------------------------------- launch
extern "C" void kernel_launch(void* const* d_in, const int* in_sizes, int n_in,
                              void* d_out, int out_size, void* d_ws, size_t ws_size,
                              hipStream_t stream) {
    const float* hidden  = (const float*)d_in[0];
    const float* cosb    = (const float*)d_in[1];
    const float* sinb    = (const float*)d_in[2];
    const float* ln1w    = (const float*)d_in[3];
    const float* ln2w    = (const float*)d_in[4];
    const float* wqkv    = (const float*)d_in[5];
    const float* wout    = (const float*)d_in[6];
    const float* wrouter = (const float*)d_in[7];
    const float* wgate   = (const float*)d_in[8];
    const float* wup     = (const float*)d_in[9];
    const float* wdown   = (const float*)d_in[10];

    float* outbuf   = (float*)d_out;
    float* out_moe  = outbuf;                          // output 0
    float* residual = outbuf + (size_t)TT * DD;        // output 1

    float* ws   = (float*)d_ws;
    float* h    = ws;                                  // T*D
    float* qkv  = h + (size_t)TT * DD;                 // T*OQ
    float* attn = qkv + (size_t)TT * OQ;               // T*D
    float* p    = attn + (size_t)TT * DD;              // 4096*F
    float* y    = p + (size_t)4096 * FF;               // 4096*D
    int*   ip   = (int*)(y + (size_t)4096 * DD);
    int* counts  = ip;           // 8
    int* cursors = ip + 8;       // 8
    int* offsets = ip + 16;      // 8
    int* tok_e   = ip + 24;      // 4096
    int* rowtok  = tok_e + 4096; // 4096
    int* slotrow = rowtok + 4096;// 4096
    float* tok_w = (float*)(slotrow + 4096); // 4096
    float* roww  = tok_w + 4096;             // 4096

    hipMemsetAsync(counts, 0, 16 * sizeof(int), stream);   // counts + cursors

    ln_kernel<<<TT, 256, 0, stream>>>(hidden, ln1w, h);
    gemm_nt<<<dim3(OQ / 64, TT / 64), 256, 0, stream>>>(h, wqkv, nullptr, qkv, OQ, DD);
    rope_kernel<<<(TT * 20 * 64) / 256, 256, 0, stream>>>(qkv, cosb, sinb);
    attn_kernel<<<dim3(SS, HH, 2), 128, 0, stream>>>(qkv, attn);
    gemm_nt<<<dim3(DD / 64, TT / 64), 256, 0, stream>>>(attn, wout, hidden, residual, DD, DD);
    ln_kernel<<<TT, 256, 0, stream>>>(residual, ln2w, h);
    router_kernel<<<TT, 256, 0, stream>>>(h, wrouter, tok_e, tok_w, counts);
    offsets_kernel<<<1, 64, 0, stream>>>(counts, offsets);
    assign_kernel<<<TT / 256, 256, 0, stream>>>(tok_e, tok_w, offsets, cursors, rowtok, roww, slotrow);
    moe_gateup<<<dim3(FF / 64, TT / 64, NE), 256, 0, stream>>>(h, wgate, wup, p, rowtok, offsets, counts);
    moe_down<<<dim3(DD / 64, TT / 64, NE), 256, 0, stream>>>(p, wdown, y, offsets, counts);
    combine_kernel<<<(TT * (DD / 4)) / 256, 256, 0, stream>>>(y, slotrow, roww, out_moe);
}

// Round 2
// 2746.301 us; speedup vs baseline: 1.3175x; 1.3175x over previous
//
#include <hip/hip_runtime.h>
#include <math.h>

// Problem constants
#define TT 2048      // T = B*S tokens
#define DD 2048      // D hidden
#define SS 1024      // S seq len
#define HH 16        // heads
#define NKV 4        // kv heads
#define HD 128       // head dim
#define NE 8         // experts
#define FF 2048      // ffn dim
#define OQ 3072      // qkv out dim (H+2*KV)*HD

// ---------------------------------------------------------------- LayerNorm
__global__ __launch_bounds__(256) void ln_kernel(const float* __restrict__ x,
                                                 const float* __restrict__ w,
                                                 float* __restrict__ out) {
    __shared__ float red[256];
    int row = blockIdx.x;
    int tid = threadIdx.x;
    const float* xr = x + (size_t)row * DD;
    float s = 0.f, s2 = 0.f;
    for (int d = tid; d < DD; d += 256) { float v = xr[d]; s += v; s2 = fmaf(v, v, s2); }
    red[tid] = s; __syncthreads();
    for (int off = 128; off > 0; off >>= 1) { if (tid < off) red[tid] += red[tid + off]; __syncthreads(); }
    float mean = red[0] / DD;
    __syncthreads();
    red[tid] = s2; __syncthreads();
    for (int off = 128; off > 0; off >>= 1) { if (tid < off) red[tid] += red[tid + off]; __syncthreads(); }
    float var = red[0] / DD - mean * mean;
    float rstd = rsqrtf(var + 1e-5f);
    for (int d = tid; d < DD; d += 256) {
        float v = xr[d];
        out[(size_t)row * DD + d] = (v - mean) * rstd * w[d];
    }
}

// ------------------------------------------------- fp32 GEMM, C = A * B^T (+add)
__global__ __launch_bounds__(256) void gemm_nt(const float* __restrict__ A,
                                               const float* __restrict__ B,
                                               const float* __restrict__ add,
                                               float* __restrict__ C,
                                               int N, int K) {
    __shared__ float As[16][64];
    __shared__ float Bs[16][64];
    int tid = threadIdx.x;
    int m0 = blockIdx.y * 64, n0 = blockIdx.x * 64;
    int tm = tid >> 4, tn = tid & 15;
    int lr = tid >> 2;
    int lk = (tid & 3) << 2;
    const float* Aload = A + (size_t)(m0 + lr) * K + lk;
    const float* Bload = B + (size_t)(n0 + lr) * K + lk;
    float acc[4][4] = {};
    for (int k0 = 0; k0 < K; k0 += 16) {
        float4 a4 = *(const float4*)(Aload + k0);
        float4 b4 = *(const float4*)(Bload + k0);
        __syncthreads();
        As[lk + 0][lr] = a4.x; As[lk + 1][lr] = a4.y; As[lk + 2][lr] = a4.z; As[lk + 3][lr] = a4.w;
        Bs[lk + 0][lr] = b4.x; Bs[lk + 1][lr] = b4.y; Bs[lk + 2][lr] = b4.z; Bs[lk + 3][lr] = b4.w;
        __syncthreads();
#pragma unroll
        for (int kk = 0; kk < 16; kk++) {
            float4 av = *(const float4*)(&As[kk][tm << 2]);
            float4 bv = *(const float4*)(&Bs[kk][tn << 2]);
            float a[4] = {av.x, av.y, av.z, av.w};
            float b[4] = {bv.x, bv.y, bv.z, bv.w};
#pragma unroll
            for (int i = 0; i < 4; i++)
#pragma unroll
                for (int j = 0; j < 4; j++) acc[i][j] = fmaf(a[i], b[j], acc[i][j]);
        }
    }
#pragma unroll
    for (int i = 0; i < 4; i++) {
        int m = m0 + (tm << 2) + i;
        float4 r = make_float4(acc[i][0], acc[i][1], acc[i][2], acc[i][3]);
        size_t idx = (size_t)m * N + n0 + (tn << 2);
        if (add) {
            float4 ad = *(const float4*)(add + idx);
            r.x += ad.x; r.y += ad.y; r.z += ad.z; r.w += ad.w;
        }
        *(float4*)(C + idx) = r;
    }
}

// ---------------------------------------------------------------- RoPE (q + k)
__global__ __launch_bounds__(256) void rope_kernel(float* __restrict__ qkv,
                                                   const float* __restrict__ cosb,
                                                   const float* __restrict__ sinb) {
    int idx = blockIdx.x * 256 + threadIdx.x;
    if (idx >= TT * 20 * 64) return;
    int d = idx & 63;
    int tmp = idx >> 6;
    int head = tmp % 20;
    int t = tmp / 20;
    int s = t & (SS - 1);
    float c0 = cosb[s * HD + d], c1 = cosb[s * HD + d + 64];
    float s0 = sinb[s * HD + d], s1 = sinb[s * HD + d + 64];
    float* base = qkv + (size_t)t * OQ + head * HD;
    float x1 = base[d], x2 = base[d + 64];
    base[d]      = x1 * c0 - x2 * s0;
    base[d + 64] = x2 * c1 + x1 * s1;
}

// ------------------------------------- flash attention, GQA, 64 q-rows x 64 keys
// Block: 256 threads. blockIdx.y = b*4+kvh; blockIdx.x -> q-tile (heavy first).
// Q-rows: r = (hi<<4) | (q - q0), hi = 0..3 (head = kvh*4+hi), 16 queries.
// LDS: Qs[d][row] 32KB staged once; KV 32KB timeshared (K as [d][key], V as [key][d]).
__global__ __launch_bounds__(256) void fattn_kernel(const float* __restrict__ qkv,
                                                    float* __restrict__ attnout) {
    int qt = 63 - blockIdx.x;          // heavy q-tiles first for load balance
    int bk = blockIdx.y;
    int b = bk >> 2, kvh = bk & 3;
    int q0 = qt * 16;
    int tid = threadIdx.x;
    int lane = tid & 63;
    int tm = tid >> 4, tn = tid & 15;

    __shared__ float Qs[128][64];      // [d][row]
    __shared__ float KV[8192];         // K: [d*64+key], V: [key*128+d]

    // ---- stage Q (once): global coalesced-ish, LDS transpose store
    {
        int r = tid >> 2;               // 0..63
        int lkb = (tid & 3) << 2;       // d sub-chunk
        int q = q0 + (r & 15);
        int h = (kvh << 2) + (r >> 4);
        const float* gq = qkv + (size_t)(b * SS + q) * OQ + h * HD;
#pragma unroll
        for (int d0 = 0; d0 < 128; d0 += 16) {
            float4 v = *(const float4*)(gq + d0 + lkb);
            Qs[d0 + lkb + 0][r] = v.x;
            Qs[d0 + lkb + 1][r] = v.y;
            Qs[d0 + lkb + 2][r] = v.z;
            Qs[d0 + lkb + 3][r] = v.w;
        }
    }

    float o[4][8] = {};
    float mrow[4] = {-1e30f, -1e30f, -1e30f, -1e30f};
    float lrow[4] = {0.f, 0.f, 0.f, 0.f};
    const float scale = 0.08838834764831845f;  // 1/sqrt(128)

    int ntiles = (q0 + 15) / 64 + 1;
    for (int tile = 0; tile < ntiles; tile++) {
        int k0 = tile * 64;
        __syncthreads();               // prev PV done reading KV; Qs visible (tile 0)
        // ---- stage K: KV[d*64+key]
        {
            int kr = tid >> 2;
            int lkb = (tid & 3) << 2;
            const float* gk = qkv + (size_t)(b * SS + k0 + kr) * OQ + 2048 + kvh * HD;
#pragma unroll
            for (int d0 = 0; d0 < 128; d0 += 16) {
                float4 v = *(const float4*)(gk + d0 + lkb);
                KV[(d0 + lkb + 0) * 64 + kr] = v.x;
                KV[(d0 + lkb + 1) * 64 + kr] = v.y;
                KV[(d0 + lkb + 2) * 64 + kr] = v.z;
                KV[(d0 + lkb + 3) * 64 + kr] = v.w;
            }
        }
        __syncthreads();
        // ---- scores: S[64 rows][64 keys] = Q * K^T, 4x4 per thread
        float s[4][4] = {};
#pragma unroll 4
        for (int kk = 0; kk < 128; kk++) {
            float4 qv = *(const float4*)(&Qs[kk][tm << 2]);
            float4 kvv = *(const float4*)(&KV[kk * 64 + (tn << 2)]);
            float qa[4] = {qv.x, qv.y, qv.z, qv.w};
            float ka[4] = {kvv.x, kvv.y, kvv.z, kvv.w};
#pragma unroll
            for (int i = 0; i < 4; i++)
#pragma unroll
                for (int j = 0; j < 4; j++) s[i][j] = fmaf(qa[i], ka[j], s[i][j]);
        }
        // ---- mask + scale + online softmax (registers + 16-lane shuffles)
        float alpha[4];
#pragma unroll
        for (int i = 0; i < 4; i++) {
            int qg = q0 + (((tm << 2) + i) & 15);
            float mloc = -1e30f;
#pragma unroll
            for (int j = 0; j < 4; j++) {
                int kg = k0 + (tn << 2) + j;
                s[i][j] = (kg <= qg) ? s[i][j] * scale : -1e30f;
                mloc = fmaxf(mloc, s[i][j]);
            }
            mloc = fmaxf(mloc, __shfl_xor(mloc, 1, 64));
            mloc = fmaxf(mloc, __shfl_xor(mloc, 2, 64));
            mloc = fmaxf(mloc, __shfl_xor(mloc, 4, 64));
            mloc = fmaxf(mloc, __shfl_xor(mloc, 8, 64));
            float mnew = fmaxf(mrow[i], mloc);
            alpha[i] = expf(mrow[i] - mnew);
            mrow[i] = mnew;
            float rs = 0.f;
#pragma unroll
            for (int j = 0; j < 4; j++) {
                s[i][j] = expf(s[i][j] - mnew);
                rs += s[i][j];
            }
            rs += __shfl_xor(rs, 1, 64);
            rs += __shfl_xor(rs, 2, 64);
            rs += __shfl_xor(rs, 4, 64);
            rs += __shfl_xor(rs, 8, 64);
            lrow[i] = lrow[i] * alpha[i] + rs;
#pragma unroll
            for (int c = 0; c < 8; c++) o[i][c] *= alpha[i];
        }
        __syncthreads();               // scores done reading K
        // ---- stage V: KV[key*128+d]
        {
            int rr = tid >> 5;
            int d4 = tid & 31;
#pragma unroll
            for (int it = 0; it < 8; it++) {
                int key = it * 8 + rr;
                const float* gv = qkv + (size_t)(b * SS + k0 + key) * OQ + 2560 + kvh * HD + (d4 << 2);
                *(float4*)(&KV[key * 128 + (d4 << 2)]) = *(const float4*)gv;
            }
        }
        __syncthreads();
        // ---- PV: o[i][c] += P[row][kk] * V[kk][tn*8+c]; P via intra-wave shuffle
#pragma unroll 4
        for (int kk = 0; kk < 64; kk++) {
            int src = (lane & 48) | (kk >> 2);
            int j = kk & 3;
            float p0 = __shfl(s[0][j], src, 64);
            float p1 = __shfl(s[1][j], src, 64);
            float p2 = __shfl(s[2][j], src, 64);
            float p3 = __shfl(s[3][j], src, 64);
            float4 va = *(const float4*)(&KV[kk * 128 + (tn << 3)]);
            float4 vb = *(const float4*)(&KV[kk * 128 + (tn << 3) + 4]);
            float vv[8] = {va.x, va.y, va.z, va.w, vb.x, vb.y, vb.z, vb.w};
#pragma unroll
            for (int c = 0; c < 8; c++) {
                o[0][c] = fmaf(p0, vv[c], o[0][c]);
                o[1][c] = fmaf(p1, vv[c], o[1][c]);
                o[2][c] = fmaf(p2, vv[c], o[2][c]);
                o[3][c] = fmaf(p3, vv[c], o[3][c]);
            }
        }
    }
    // ---- epilogue
#pragma unroll
    for (int i = 0; i < 4; i++) {
        int r = (tm << 2) + i;
        int q = q0 + (r & 15);
        int h = (kvh << 2) + (r >> 4);
        float inv = 1.f / lrow[i];
        float4 r0 = make_float4(o[i][0] * inv, o[i][1] * inv, o[i][2] * inv, o[i][3] * inv);
        float4 r1 = make_float4(o[i][4] * inv, o[i][5] * inv, o[i][6] * inv, o[i][7] * inv);
        float* op = attnout + (size_t)(b * SS + q) * DD + h * HD + (tn << 3);
        *(float4*)op = r0;
        *(float4*)(op + 4) = r1;
    }
}

// ---------------------------------------------------------------- Router
__global__ __launch_bounds__(256) void router_kernel(const float* __restrict__ x,
                                                     const float* __restrict__ wr,
                                                     int* __restrict__ tok_e,
                                                     float* __restrict__ tok_w,
                                                     int* __restrict__ counts) {
    __shared__ float red[256];
    __shared__ float logits[NE];
    int t = blockIdx.x;
    int tid = threadIdx.x;
    const float* xr = x + (size_t)t * DD;
    float acc[NE] = {};
    for (int d = tid; d < DD; d += 256) {
        float xv = xr[d];
#pragma unroll
        for (int e = 0; e < NE; e++) acc[e] = fmaf(xv, wr[e * DD + d], acc[e]);
    }
    for (int e = 0; e < NE; e++) {
        red[tid] = acc[e]; __syncthreads();
        for (int off = 128; off > 0; off >>= 1) { if (tid < off) red[tid] += red[tid + off]; __syncthreads(); }
        if (tid == 0) logits[e] = red[0];
        __syncthreads();
    }
    if (tid == 0) {
        float mx = logits[0];
        for (int e = 1; e < NE; e++) mx = fmaxf(mx, logits[e]);
        float ex[NE];
        for (int e = 0; e < NE; e++) ex[e] = expf(logits[e] - mx);
        int e0 = 0;
        for (int e = 1; e < NE; e++) if (ex[e] > ex[e0]) e0 = e;
        int e1 = -1;
        for (int e = 0; e < NE; e++) if (e != e0 && (e1 < 0 || ex[e] > ex[e1])) e1 = e;
        float w0 = ex[e0], w1 = ex[e1];
        float sw = w0 + w1;
        w0 /= sw; w1 /= sw;
        tok_e[2 * t] = e0; tok_e[2 * t + 1] = e1;
        tok_w[2 * t] = w0; tok_w[2 * t + 1] = w1;
        atomicAdd(&counts[e0], 1);
        atomicAdd(&counts[e1], 1);
    }
}

__global__ void offsets_kernel(const int* __restrict__ counts, int* __restrict__ offsets) {
    if (threadIdx.x == 0 && blockIdx.x == 0) {
        int acc = 0;
        for (int e = 0; e < NE; e++) { offsets[e] = acc; acc += counts[e]; }
    }
}

__global__ __launch_bounds__(256) void assign_kernel(const int* __restrict__ tok_e,
                                                     const float* __restrict__ tok_w,
                                                     const int* __restrict__ offsets,
                                                     int* __restrict__ cursors,
                                                     int* __restrict__ rowtok,
                                                     float* __restrict__ roww,
                                                     int* __restrict__ slotrow) {
    int t = blockIdx.x * 256 + threadIdx.x;
    if (t >= TT) return;
    for (int k = 0; k < 2; k++) {
        int e = tok_e[2 * t + k];
        int pos = atomicAdd(&cursors[e], 1);
        int row = offsets[e] + pos;
        rowtok[row] = t;
        roww[row] = tok_w[2 * t + k];
        slotrow[2 * t + k] = row;
    }
}

// ----------------------------- MoE gate+up fused GEMM (NN), gathered A rows
__global__ __launch_bounds__(256) void moe_gateup(const float* __restrict__ X,
                                                  const float* __restrict__ Wg,
                                                  const float* __restrict__ Wu,
                                                  float* __restrict__ P,
                                                  const int* __restrict__ rowtok,
                                                  const int* __restrict__ offsets,
                                                  const int* __restrict__ counts) {
    int e = blockIdx.z;
    int cnt = counts[e];
    int m0 = blockIdx.y * 64;
    if (m0 >= cnt) return;
    int n0 = blockIdx.x * 64;
    int off = offsets[e];
    __shared__ float As[16][64];
    __shared__ float Bg[16][64];
    __shared__ float Bu[16][64];
    __shared__ int rowt[64];
    int tid = threadIdx.x;
    if (tid < 64) {
        int m = m0 + tid;
        rowt[tid] = (m < cnt) ? rowtok[off + m] : -1;
    }
    __syncthreads();
    int lr = tid >> 2, lk = (tid & 3) << 2;
    int bkr = tid >> 4, bnc = (tid & 15) << 2;
    int arow = rowt[lr];
    const float* wg = Wg + (size_t)e * DD * FF;
    const float* wu = Wu + (size_t)e * DD * FF;
    float accg[4][4] = {}, accu[4][4] = {};
    int tm = tid >> 4, tn = tid & 15;
    for (int k0 = 0; k0 < DD; k0 += 16) {
        float4 a4 = make_float4(0.f, 0.f, 0.f, 0.f);
        if (arow >= 0) a4 = *(const float4*)(X + (size_t)arow * DD + k0 + lk);
        float4 g4 = *(const float4*)(wg + (size_t)(k0 + bkr) * FF + n0 + bnc);
        float4 u4 = *(const float4*)(wu + (size_t)(k0 + bkr) * FF + n0 + bnc);
        __syncthreads();
        As[lk + 0][lr] = a4.x; As[lk + 1][lr] = a4.y; As[lk + 2][lr] = a4.z; As[lk + 3][lr] = a4.w;
        *(float4*)&Bg[bkr][bnc] = g4;
        *(float4*)&Bu[bkr][bnc] = u4;
        __syncthreads();
#pragma unroll
        for (int kk = 0; kk < 16; kk++) {
            float4 av = *(const float4*)(&As[kk][tm << 2]);
            float4 gv = *(const float4*)(&Bg[kk][tn << 2]);
            float4 uv = *(const float4*)(&Bu[kk][tn << 2]);
            float a[4] = {av.x, av.y, av.z, av.w};
            float g[4] = {gv.x, gv.y, gv.z, gv.w};
            float u[4] = {uv.x, uv.y, uv.z, uv.w};
#pragma unroll
            for (int i = 0; i < 4; i++)
#pragma unroll
                for (int j = 0; j < 4; j++) {
                    accg[i][j] = fmaf(a[i], g[j], accg[i][j]);
                    accu[i][j] = fmaf(a[i], u[j], accu[i][j]);
                }
        }
    }
#pragma unroll
    for (int i = 0; i < 4; i++) {
        int m = m0 + (tm << 2) + i;
        if (m < cnt) {
            float4 r;
            float* rp = &r.x;
#pragma unroll
            for (int j = 0; j < 4; j++) {
                float g = accg[i][j], u = accu[i][j];
                rp[j] = (g / (1.f + expf(-g))) * u;
            }
            *(float4*)(P + (size_t)(off + m) * FF + n0 + (tn << 2)) = r;
        }
    }
}

// ----------------------------- MoE down GEMM (NN), contiguous A rows
__global__ __launch_bounds__(256) void moe_down(const float* __restrict__ P,
                                                const float* __restrict__ Wd,
                                                float* __restrict__ Y,
                                                const int* __restrict__ offsets,
                                                const int* __restrict__ counts) {
    int e = blockIdx.z;
    int cnt = counts[e];
    int m0 = blockIdx.y * 64;
    if (m0 >= cnt) return;
    int n0 = blockIdx.x * 64;
    int off = offsets[e];
    __shared__ float As[16][64];
    __shared__ float Bs[16][64];
    int tid = threadIdx.x;
    int lr = tid >> 2, lk = (tid & 3) << 2;
    int bkr = tid >> 4, bnc = (tid & 15) << 2;
    const float* wd = Wd + (size_t)e * FF * DD;
    const float* aload = P + (size_t)(off + m0 + lr) * FF + lk;
    float acc[4][4] = {};
    int tm = tid >> 4, tn = tid & 15;
    for (int k0 = 0; k0 < FF; k0 += 16) {
        float4 a4 = *(const float4*)(aload + k0);
        float4 b4 = *(const float4*)(wd + (size_t)(k0 + bkr) * DD + n0 + bnc);
        __syncthreads();
        As[lk + 0][lr] = a4.x; As[lk + 1][lr] = a4.y; As[lk + 2][lr] = a4.z; As[lk + 3][lr] = a4.w;
        *(float4*)&Bs[bkr][bnc] = b4;
        __syncthreads();
#pragma unroll
        for (int kk = 0; kk < 16; kk++) {
            float4 av = *(const float4*)(&As[kk][tm << 2]);
            float4 bv = *(const float4*)(&Bs[kk][tn << 2]);
            float a[4] = {av.x, av.y, av.z, av.w};
            float b[4] = {bv.x, bv.y, bv.z, bv.w};
#pragma unroll
            for (int i = 0; i < 4; i++)
#pragma unroll
                for (int j = 0; j < 4; j++) acc[i][j] = fmaf(a[i], b[j], acc[i][j]);
        }
    }
#pragma unroll
    for (int i = 0; i < 4; i++) {
        int m = m0 + (tm << 2) + i;
        if (m < cnt) {
            float4 r = make_float4(acc[i][0], acc[i][1], acc[i][2], acc[i][3]);
            *(float4*)(Y + (size_t)(off + m) * DD + n0 + (tn << 2)) = r;
        }
    }
}

// ---------------------------------------------------------------- combine
__global__ __launch_bounds__(256) void combine_kernel(const float* __restrict__ Y,
                                                      const int* __restrict__ slotrow,
                                                      const float* __restrict__ roww,
                                                      float* __restrict__ out) {
    int i = blockIdx.x * 256 + threadIdx.x;
    if (i >= TT * (DD / 4)) return;
    int t = i >> 9;
    int d4 = i & 511;
    int r0 = slotrow[2 * t], r1 = slotrow[2 * t + 1];
    float w0 = roww[r0], w1 = roww[r1];
    float4 y0 = ((const float4*)Y)[(size_t)r0 * 512 + d4];
    float4 y1 = ((const float4*)Y)[(size_t)r1 * 512 + d4];
    float4 r;
    r.x = w0 * y0.x + w1 * y1.x;
    r.y = w0 * y0.y + w1 * y1.y;
    r.z = w0 * y0.z + w1 * y1.z;
    r.w = w0 * y0.w + w1 * y1.w;
    ((float4*)out)[i] = r;
}

// ---------------------------------------------------------------- launch
extern "C" void kernel_launch(void* const* d_in, const int* in_sizes, int n_in,
                              void* d_out, int out_size, void* d_ws, size_t ws_size,
                              hipStream_t stream) {
    const float* hidden  = (const float*)d_in[0];
    const float* cosb    = (const float*)d_in[1];
    const float* sinb    = (const float*)d_in[2];
    const float* ln1w    = (const float*)d_in[3];
    const float* ln2w    = (const float*)d_in[4];
    const float* wqkv    = (const float*)d_in[5];
    const float* wout    = (const float*)d_in[6];
    const float* wrouter = (const float*)d_in[7];
    const float* wgate   = (const float*)d_in[8];
    const float* wup     = (const float*)d_in[9];
    const float* wdown   = (const float*)d_in[10];

    float* outbuf   = (float*)d_out;
    float* out_moe  = outbuf;
    float* residual = outbuf + (size_t)TT * DD;

    float* ws   = (float*)d_ws;
    float* h    = ws;
    float* qkv  = h + (size_t)TT * DD;
    float* attn = qkv + (size_t)TT * OQ;
    float* p    = attn + (size_t)TT * DD;
    float* y    = p + (size_t)4096 * FF;
    int*   ip   = (int*)(y + (size_t)4096 * DD);
    int* counts  = ip;
    int* cursors = ip + 8;
    int* offsets = ip + 16;
    int* tok_e   = ip + 24;
    int* rowtok  = tok_e + 4096;
    int* slotrow = rowtok + 4096;
    float* tok_w = (float*)(slotrow + 4096);
    float* roww  = tok_w + 4096;

    hipMemsetAsync(counts, 0, 16 * sizeof(int), stream);

    ln_kernel<<<TT, 256, 0, stream>>>(hidden, ln1w, h);
    gemm_nt<<<dim3(OQ / 64, TT / 64), 256, 0, stream>>>(h, wqkv, nullptr, qkv, OQ, DD);
    rope_kernel<<<(TT * 20 * 64) / 256, 256, 0, stream>>>(qkv, cosb, sinb);
    fattn_kernel<<<dim3(64, 8), 256, 0, stream>>>(qkv, attn);
    gemm_nt<<<dim3(DD / 64, TT / 64), 256, 0, stream>>>(attn, wout, hidden, residual, DD, DD);
    ln_kernel<<<TT, 256, 0, stream>>>(residual, ln2w, h);
    router_kernel<<<TT, 256, 0, stream>>>(h, wrouter, tok_e, tok_w, counts);
    offsets_kernel<<<1, 64, 0, stream>>>(counts, offsets);
    assign_kernel<<<TT / 256, 256, 0, stream>>>(tok_e, tok_w, offsets, cursors, rowtok, roww, slotrow);
    moe_gateup<<<dim3(FF / 64, TT / 64, NE), 256, 0, stream>>>(h, wgate, wup, p, rowtok, offsets, counts);
    moe_down<<<dim3(DD / 64, TT / 64, NE), 256, 0, stream>>>(p, wdown, y, offsets, counts);
    combine_kernel<<<(TT * (DD / 4)) / 256, 256, 0, stream>>>(y, slotrow, roww, out_moe);
}

// Round 3
// 1647.876 us; speedup vs baseline: 2.1958x; 1.6666x over previous
//
#include <hip/hip_runtime.h>
#include <math.h>

// Problem constants
#define TT 2048      // T = B*S tokens
#define DD 2048      // D hidden
#define SS 1024      // S seq len
#define HH 16        // heads
#define NKV 4        // kv heads
#define HD 128       // head dim
#define NE 8         // experts
#define FF 2048      // ffn dim
#define OQ 3072      // qkv out dim (H+2*KV)*HD
#define MOE_ROWS 4096
#define MOE_PAD  4224   // +128 rows slack for 128-tile overrun

typedef __bf16 bf16;
typedef __attribute__((ext_vector_type(8))) __bf16 bf16x8;
typedef __attribute__((ext_vector_type(4))) float f32x4;

// RNE fp32 -> bf16 helpers
__device__ __forceinline__ unsigned pkbf(float a, float b) {
    unsigned ua = __float_as_uint(a); ua += 0x7fff + ((ua >> 16) & 1);
    unsigned ub = __float_as_uint(b); ub += 0x7fff + ((ub >> 16) & 1);
    return (ua >> 16) | (ub & 0xffff0000u);
}
__device__ __forceinline__ unsigned short f2bf(float a) {
    unsigned ua = __float_as_uint(a); ua += 0x7fff + ((ua >> 16) & 1);
    return (unsigned short)(ua >> 16);
}
__device__ __forceinline__ float bf2f(unsigned short u) {
    return __uint_as_float(((unsigned)u) << 16);
}

__device__ __forceinline__ void gll16(const void* g, void* l) {
    __builtin_amdgcn_global_load_lds((const __attribute__((address_space(1))) void*)g,
                                     (__attribute__((address_space(3))) void*)l, 16, 0, 0);
}

// ---------------------------------------------------------------- LayerNorm
__global__ __launch_bounds__(256) void ln_kernel(const float* __restrict__ x,
                                                 const float* __restrict__ w,
                                                 float* __restrict__ out) {
    __shared__ float red[256];
    int row = blockIdx.x;
    int tid = threadIdx.x;
    const float* xr = x + (size_t)row * DD;
    float s = 0.f, s2 = 0.f;
    for (int d = tid; d < DD; d += 256) { float v = xr[d]; s += v; s2 = fmaf(v, v, s2); }
    red[tid] = s; __syncthreads();
    for (int off = 128; off > 0; off >>= 1) { if (tid < off) red[tid] += red[tid + off]; __syncthreads(); }
    float mean = red[0] / DD;
    __syncthreads();
    red[tid] = s2; __syncthreads();
    for (int off = 128; off > 0; off >>= 1) { if (tid < off) red[tid] += red[tid + off]; __syncthreads(); }
    float var = red[0] / DD - mean * mean;
    float rstd = rsqrtf(var + 1e-5f);
    for (int d = tid; d < DD; d += 256) {
        float v = xr[d];
        out[(size_t)row * DD + d] = (v - mean) * rstd * w[d];
    }
}

// ------------------------------------------------- fp32 GEMM, C = A * B^T (+add)
__global__ __launch_bounds__(256) void gemm_nt(const float* __restrict__ A,
                                               const float* __restrict__ B,
                                               const float* __restrict__ add,
                                               float* __restrict__ C,
                                               int N, int K) {
    __shared__ float As[16][64];
    __shared__ float Bs[16][64];
    int tid = threadIdx.x;
    int m0 = blockIdx.y * 64, n0 = blockIdx.x * 64;
    int tm = tid >> 4, tn = tid & 15;
    int lr = tid >> 2;
    int lk = (tid & 3) << 2;
    const float* Aload = A + (size_t)(m0 + lr) * K + lk;
    const float* Bload = B + (size_t)(n0 + lr) * K + lk;
    float acc[4][4] = {};
    for (int k0 = 0; k0 < K; k0 += 16) {
        float4 a4 = *(const float4*)(Aload + k0);
        float4 b4 = *(const float4*)(Bload + k0);
        __syncthreads();
        As[lk + 0][lr] = a4.x; As[lk + 1][lr] = a4.y; As[lk + 2][lr] = a4.z; As[lk + 3][lr] = a4.w;
        Bs[lk + 0][lr] = b4.x; Bs[lk + 1][lr] = b4.y; Bs[lk + 2][lr] = b4.z; Bs[lk + 3][lr] = b4.w;
        __syncthreads();
#pragma unroll
        for (int kk = 0; kk < 16; kk++) {
            float4 av = *(const float4*)(&As[kk][tm << 2]);
            float4 bv = *(const float4*)(&Bs[kk][tn << 2]);
            float a[4] = {av.x, av.y, av.z, av.w};
            float b[4] = {bv.x, bv.y, bv.z, bv.w};
#pragma unroll
            for (int i = 0; i < 4; i++)
#pragma unroll
                for (int j = 0; j < 4; j++) acc[i][j] = fmaf(a[i], b[j], acc[i][j]);
        }
    }
#pragma unroll
    for (int i = 0; i < 4; i++) {
        int m = m0 + (tm << 2) + i;
        float4 r = make_float4(acc[i][0], acc[i][1], acc[i][2], acc[i][3]);
        size_t idx = (size_t)m * N + n0 + (tn << 2);
        if (add) {
            float4 ad = *(const float4*)(add + idx);
            r.x += ad.x; r.y += ad.y; r.z += ad.z; r.w += ad.w;
        }
        *(float4*)(C + idx) = r;
    }
}

// ---------------------------------------------------------------- RoPE (q + k)
__global__ __launch_bounds__(256) void rope_kernel(float* __restrict__ qkv,
                                                   const float* __restrict__ cosb,
                                                   const float* __restrict__ sinb) {
    int idx = blockIdx.x * 256 + threadIdx.x;
    if (idx >= TT * 20 * 64) return;
    int d = idx & 63;
    int tmp = idx >> 6;
    int head = tmp % 20;
    int t = tmp / 20;
    int s = t & (SS - 1);
    float c0 = cosb[s * HD + d], c1 = cosb[s * HD + d + 64];
    float s0 = sinb[s * HD + d], s1 = sinb[s * HD + d + 64];
    float* base = qkv + (size_t)t * OQ + head * HD;
    float x1 = base[d], x2 = base[d + 64];
    base[d]      = x1 * c0 - x2 * s0;
    base[d + 64] = x2 * c1 + x1 * s1;
}

// ------------------------------------- flash attention, GQA, 64 q-rows x 64 keys
__global__ __launch_bounds__(256) void fattn_kernel(const float* __restrict__ qkv,
                                                    float* __restrict__ attnout) {
    int qt = 63 - blockIdx.x;
    int bk = blockIdx.y;
    int b = bk >> 2, kvh = bk & 3;
    int q0 = qt * 16;
    int tid = threadIdx.x;
    int lane = tid & 63;
    int tm = tid >> 4, tn = tid & 15;

    __shared__ float Qs[128][64];
    __shared__ float KV[8192];

    {
        int r = tid >> 2;
        int lkb = (tid & 3) << 2;
        int q = q0 + (r & 15);
        int h = (kvh << 2) + (r >> 4);
        const float* gq = qkv + (size_t)(b * SS + q) * OQ + h * HD;
#pragma unroll
        for (int d0 = 0; d0 < 128; d0 += 16) {
            float4 v = *(const float4*)(gq + d0 + lkb);
            Qs[d0 + lkb + 0][r] = v.x;
            Qs[d0 + lkb + 1][r] = v.y;
            Qs[d0 + lkb + 2][r] = v.z;
            Qs[d0 + lkb + 3][r] = v.w;
        }
    }

    float o[4][8] = {};
    float mrow[4] = {-1e30f, -1e30f, -1e30f, -1e30f};
    float lrow[4] = {0.f, 0.f, 0.f, 0.f};
    const float scale = 0.08838834764831845f;

    int ntiles = (q0 + 15) / 64 + 1;
    for (int tile = 0; tile < ntiles; tile++) {
        int k0 = tile * 64;
        __syncthreads();
        {
            int kr = tid >> 2;
            int lkb = (tid & 3) << 2;
            const float* gk = qkv + (size_t)(b * SS + k0 + kr) * OQ + 2048 + kvh * HD;
#pragma unroll
            for (int d0 = 0; d0 < 128; d0 += 16) {
                float4 v = *(const float4*)(gk + d0 + lkb);
                KV[(d0 + lkb + 0) * 64 + kr] = v.x;
                KV[(d0 + lkb + 1) * 64 + kr] = v.y;
                KV[(d0 + lkb + 2) * 64 + kr] = v.z;
                KV[(d0 + lkb + 3) * 64 + kr] = v.w;
            }
        }
        __syncthreads();
        float s[4][4] = {};
#pragma unroll 4
        for (int kk = 0; kk < 128; kk++) {
            float4 qv = *(const float4*)(&Qs[kk][tm << 2]);
            float4 kvv = *(const float4*)(&KV[kk * 64 + (tn << 2)]);
            float qa[4] = {qv.x, qv.y, qv.z, qv.w};
            float ka[4] = {kvv.x, kvv.y, kvv.z, kvv.w};
#pragma unroll
            for (int i = 0; i < 4; i++)
#pragma unroll
                for (int j = 0; j < 4; j++) s[i][j] = fmaf(qa[i], ka[j], s[i][j]);
        }
        float alpha[4];
#pragma unroll
        for (int i = 0; i < 4; i++) {
            int qg = q0 + (((tm << 2) + i) & 15);
            float mloc = -1e30f;
#pragma unroll
            for (int j = 0; j < 4; j++) {
                int kg = k0 + (tn << 2) + j;
                s[i][j] = (kg <= qg) ? s[i][j] * scale : -1e30f;
                mloc = fmaxf(mloc, s[i][j]);
            }
            mloc = fmaxf(mloc, __shfl_xor(mloc, 1, 64));
            mloc = fmaxf(mloc, __shfl_xor(mloc, 2, 64));
            mloc = fmaxf(mloc, __shfl_xor(mloc, 4, 64));
            mloc = fmaxf(mloc, __shfl_xor(mloc, 8, 64));
            float mnew = fmaxf(mrow[i], mloc);
            alpha[i] = expf(mrow[i] - mnew);
            mrow[i] = mnew;
            float rs = 0.f;
#pragma unroll
            for (int j = 0; j < 4; j++) {
                s[i][j] = expf(s[i][j] - mnew);
                rs += s[i][j];
            }
            rs += __shfl_xor(rs, 1, 64);
            rs += __shfl_xor(rs, 2, 64);
            rs += __shfl_xor(rs, 4, 64);
            rs += __shfl_xor(rs, 8, 64);
            lrow[i] = lrow[i] * alpha[i] + rs;
#pragma unroll
            for (int c = 0; c < 8; c++) o[i][c] *= alpha[i];
        }
        __syncthreads();
        {
            int rr = tid >> 5;
            int d4 = tid & 31;
#pragma unroll
            for (int it = 0; it < 8; it++) {
                int key = it * 8 + rr;
                const float* gv = qkv + (size_t)(b * SS + k0 + key) * OQ + 2560 + kvh * HD + (d4 << 2);
                *(float4*)(&KV[key * 128 + (d4 << 2)]) = *(const float4*)gv;
            }
        }
        __syncthreads();
#pragma unroll 4
        for (int kk = 0; kk < 64; kk++) {
            int src = (lane & 48) | (kk >> 2);
            int j = kk & 3;
            float p0 = __shfl(s[0][j], src, 64);
            float p1 = __shfl(s[1][j], src, 64);
            float p2 = __shfl(s[2][j], src, 64);
            float p3 = __shfl(s[3][j], src, 64);
            float4 va = *(const float4*)(&KV[kk * 128 + (tn << 3)]);
            float4 vb = *(const float4*)(&KV[kk * 128 + (tn << 3) + 4]);
            float vv[8] = {va.x, va.y, va.z, va.w, vb.x, vb.y, vb.z, vb.w};
#pragma unroll
            for (int c = 0; c < 8; c++) {
                o[0][c] = fmaf(p0, vv[c], o[0][c]);
                o[1][c] = fmaf(p1, vv[c], o[1][c]);
                o[2][c] = fmaf(p2, vv[c], o[2][c]);
                o[3][c] = fmaf(p3, vv[c], o[3][c]);
            }
        }
    }
#pragma unroll
    for (int i = 0; i < 4; i++) {
        int r = (tm << 2) + i;
        int q = q0 + (r & 15);
        int h = (kvh << 2) + (r >> 4);
        float inv = 1.f / lrow[i];
        float4 r0 = make_float4(o[i][0] * inv, o[i][1] * inv, o[i][2] * inv, o[i][3] * inv);
        float4 r1 = make_float4(o[i][4] * inv, o[i][5] * inv, o[i][6] * inv, o[i][7] * inv);
        float* op = attnout + (size_t)(b * SS + q) * DD + h * HD + (tn << 3);
        *(float4*)op = r0;
        *(float4*)(op + 4) = r1;
    }
}

// ---------------------------------------------------------------- Router
__global__ __launch_bounds__(256) void router_kernel(const float* __restrict__ x,
                                                     const float* __restrict__ wr,
                                                     int* __restrict__ tok_e,
                                                     float* __restrict__ tok_w,
                                                     int* __restrict__ counts) {
    __shared__ float red[256];
    __shared__ float logits[NE];
    int t = blockIdx.x;
    int tid = threadIdx.x;
    const float* xr = x + (size_t)t * DD;
    float acc[NE] = {};
    for (int d = tid; d < DD; d += 256) {
        float xv = xr[d];
#pragma unroll
        for (int e = 0; e < NE; e++) acc[e] = fmaf(xv, wr[e * DD + d], acc[e]);
    }
    for (int e = 0; e < NE; e++) {
        red[tid] = acc[e]; __syncthreads();
        for (int off = 128; off > 0; off >>= 1) { if (tid < off) red[tid] += red[tid + off]; __syncthreads(); }
        if (tid == 0) logits[e] = red[0];
        __syncthreads();
    }
    if (tid == 0) {
        float mx = logits[0];
        for (int e = 1; e < NE; e++) mx = fmaxf(mx, logits[e]);
        float ex[NE];
        for (int e = 0; e < NE; e++) ex[e] = expf(logits[e] - mx);
        int e0 = 0;
        for (int e = 1; e < NE; e++) if (ex[e] > ex[e0]) e0 = e;
        int e1 = -1;
        for (int e = 0; e < NE; e++) if (e != e0 && (e1 < 0 || ex[e] > ex[e1])) e1 = e;
        float w0 = ex[e0], w1 = ex[e1];
        float sw = w0 + w1;
        w0 /= sw; w1 /= sw;
        tok_e[2 * t] = e0; tok_e[2 * t + 1] = e1;
        tok_w[2 * t] = w0; tok_w[2 * t + 1] = w1;
        atomicAdd(&counts[e0], 1);
        atomicAdd(&counts[e1], 1);
    }
}

__global__ void offsets_kernel(const int* __restrict__ counts, int* __restrict__ offsets) {
    if (threadIdx.x == 0 && blockIdx.x == 0) {
        int acc = 0;
        for (int e = 0; e < NE; e++) { offsets[e] = acc; acc += counts[e]; }
    }
}

__global__ __launch_bounds__(256) void assign_kernel(const int* __restrict__ tok_e,
                                                     const float* __restrict__ tok_w,
                                                     const int* __restrict__ offsets,
                                                     int* __restrict__ cursors,
                                                     int* __restrict__ rowtok,
                                                     float* __restrict__ roww,
                                                     int* __restrict__ slotrow) {
    int t = blockIdx.x * 256 + threadIdx.x;
    if (t >= TT) return;
    for (int k = 0; k < 2; k++) {
        int e = tok_e[2 * t + k];
        int pos = atomicAdd(&cursors[e], 1);
        int row = offsets[e] + pos;
        rowtok[row] = t;
        roww[row] = tok_w[2 * t + k];
        slotrow[2 * t + k] = row;
    }
}

// --------------------------------- gather h (fp32) -> Xg rows (bf16)
__global__ __launch_bounds__(256) void gather_kernel(const float* __restrict__ h,
                                                     const int* __restrict__ rowtok,
                                                     bf16* __restrict__ Xg) {
    int row = blockIdx.x;
    int tid = threadIdx.x;
    const float* src = h + (size_t)rowtok[row] * DD;
    bf16* dst = Xg + (size_t)row * DD;
    int d = tid * 8;
    float4 v0 = *(const float4*)(src + d);
    float4 v1 = *(const float4*)(src + d + 4);
    uint4 o;
    o.x = pkbf(v0.x, v0.y); o.y = pkbf(v0.z, v0.w);
    o.z = pkbf(v1.x, v1.y); o.w = pkbf(v1.z, v1.w);
    *(uint4*)(dst + d) = o;
}

// --------------------------------- MoE bf16 MFMA GEMM, C = A * W[e]  (W is [K][N])
// MODE 0: gate -> store C as bf16 (gbuf)
// MODE 1: up   -> P = silu(g) * C, store bf16
// MODE 2: down -> store C as bf16 (Y)
// Tile 128x128, BK=32, 4 waves, mfma_f32_16x16x32_bf16.
template<int MODE>
__global__ __launch_bounds__(256) void moe_mfma(const bf16* __restrict__ A,
                                                const float* __restrict__ W,
                                                bf16* __restrict__ Cout,
                                                const bf16* __restrict__ Gin,
                                                const int* __restrict__ offsets,
                                                const int* __restrict__ counts) {
    const int K = 2048, N = 2048;
    int e = blockIdx.z;
    int cnt = counts[e];
    int m0 = blockIdx.y * 128;
    if (m0 >= cnt) return;
    int off = offsets[e];
    int n0 = blockIdx.x * 128;
    int tid = threadIdx.x;
    int lane = tid & 63, wave = tid >> 6;

    __shared__ bf16 As[128 * 32];
    __shared__ bf16 Bs[128 * 32];

    // A staging via global_load_lds (16B per lane). chunk c = inst*256+tid; r=c>>2, kc=c&3.
    const bf16* a0 = A + (size_t)(off + m0 + (tid >> 2)) * K + (tid & 3) * 8;
    const bf16* a1 = A + (size_t)(off + m0 + 64 + (tid >> 2)) * K + (tid & 3) * 8;
    bf16* l0 = As + (wave * 64) * 8;          // wave-uniform LDS base, inst 0
    bf16* l1 = As + (256 + wave * 64) * 8;    // inst 1

    // B staging: fp32 [K][N] -> bf16 LDS [n][k] (row = 32 bf16 = 64B)
    int bn = tid & 127;
    int bks = (tid >> 7) * 16;
    const float* bptr = W + (size_t)e * K * N + (size_t)bks * N + n0 + bn;
    bf16* bdst = Bs + bn * 32 + bks;

    // fragment read pointers
    int wm = (wave >> 1) * 64, wn = (wave & 1) * 64;
    int fr = lane & 15, k8 = lane >> 4;
    const bf16x8* apf0 = (const bf16x8*)(As + (wm + 0 * 16 + fr) * 32 + k8 * 8);
    const bf16x8* apf1 = (const bf16x8*)(As + (wm + 1 * 16 + fr) * 32 + k8 * 8);
    const bf16x8* apf2 = (const bf16x8*)(As + (wm + 2 * 16 + fr) * 32 + k8 * 8);
    const bf16x8* apf3 = (const bf16x8*)(As + (wm + 3 * 16 + fr) * 32 + k8 * 8);
    const bf16x8* bpf0 = (const bf16x8*)(Bs + (wn + 0 * 16 + fr) * 32 + k8 * 8);
    const bf16x8* bpf1 = (const bf16x8*)(Bs + (wn + 1 * 16 + fr) * 32 + k8 * 8);
    const bf16x8* bpf2 = (const bf16x8*)(Bs + (wn + 2 * 16 + fr) * 32 + k8 * 8);
    const bf16x8* bpf3 = (const bf16x8*)(Bs + (wn + 3 * 16 + fr) * 32 + k8 * 8);

    f32x4 acc[4][4] = {};

    for (int kt = 0; kt < K / 32; kt++) {
        // B global loads (no LDS hazard -> issue before barrier)
        float v[16];
#pragma unroll
        for (int i = 0; i < 16; i++) v[i] = bptr[(size_t)i * N];
        bptr += (size_t)32 * N;

        __syncthreads();   // previous iteration's fragment reads complete

        gll16(a0, l0);
        gll16(a1, l1);
        a0 += 32; a1 += 32;

        uint4 w0, w1;
        w0.x = pkbf(v[0], v[1]);  w0.y = pkbf(v[2], v[3]);
        w0.z = pkbf(v[4], v[5]);  w0.w = pkbf(v[6], v[7]);
        w1.x = pkbf(v[8], v[9]);  w1.y = pkbf(v[10], v[11]);
        w1.z = pkbf(v[12], v[13]); w1.w = pkbf(v[14], v[15]);
        *(uint4*)bdst = w0;
        *(uint4*)(bdst + 8) = w1;

        __syncthreads();   // drains vmcnt (global_load_lds) + lgkm (ds_write)

        bf16x8 af0 = *apf0, af1 = *apf1, af2 = *apf2, af3 = *apf3;
        bf16x8 bf0 = *bpf0, bf1 = *bpf1, bf2 = *bpf2, bf3 = *bpf3;
        acc[0][0] = __builtin_amdgcn_mfma_f32_16x16x32_bf16(af0, bf0, acc[0][0], 0, 0, 0);
        acc[0][1] = __builtin_amdgcn_mfma_f32_16x16x32_bf16(af0, bf1, acc[0][1], 0, 0, 0);
        acc[0][2] = __builtin_amdgcn_mfma_f32_16x16x32_bf16(af0, bf2, acc[0][2], 0, 0, 0);
        acc[0][3] = __builtin_amdgcn_mfma_f32_16x16x32_bf16(af0, bf3, acc[0][3], 0, 0, 0);
        acc[1][0] = __builtin_amdgcn_mfma_f32_16x16x32_bf16(af1, bf0, acc[1][0], 0, 0, 0);
        acc[1][1] = __builtin_amdgcn_mfma_f32_16x16x32_bf16(af1, bf1, acc[1][1], 0, 0, 0);
        acc[1][2] = __builtin_amdgcn_mfma_f32_16x16x32_bf16(af1, bf2, acc[1][2], 0, 0, 0);
        acc[1][3] = __builtin_amdgcn_mfma_f32_16x16x32_bf16(af1, bf3, acc[1][3], 0, 0, 0);
        acc[2][0] = __builtin_amdgcn_mfma_f32_16x16x32_bf16(af2, bf0, acc[2][0], 0, 0, 0);
        acc[2][1] = __builtin_amdgcn_mfma_f32_16x16x32_bf16(af2, bf1, acc[2][1], 0, 0, 0);
        acc[2][2] = __builtin_amdgcn_mfma_f32_16x16x32_bf16(af2, bf2, acc[2][2], 0, 0, 0);
        acc[2][3] = __builtin_amdgcn_mfma_f32_16x16x32_bf16(af2, bf3, acc[2][3], 0, 0, 0);
        acc[3][0] = __builtin_amdgcn_mfma_f32_16x16x32_bf16(af3, bf0, acc[3][0], 0, 0, 0);
        acc[3][1] = __builtin_amdgcn_mfma_f32_16x16x32_bf16(af3, bf1, acc[3][1], 0, 0, 0);
        acc[3][2] = __builtin_amdgcn_mfma_f32_16x16x32_bf16(af3, bf2, acc[3][2], 0, 0, 0);
        acc[3][3] = __builtin_amdgcn_mfma_f32_16x16x32_bf16(af3, bf3, acc[3][3], 0, 0, 0);
    }

    // epilogue: C[row][col], row = m0+wm+i*16+(lane>>4)*4+r, col = n0+wn+j*16+(lane&15)
    int q4 = (lane >> 4) * 4;
#pragma unroll
    for (int i = 0; i < 4; i++) {
#pragma unroll
        for (int r = 0; r < 4; r++) {
            int row = m0 + wm + i * 16 + q4 + r;
            if (row < cnt) {
                size_t rbase = (size_t)(off + row) * 2048;
#pragma unroll
                for (int j = 0; j < 4; j++) {
                    int col = n0 + wn + j * 16 + (lane & 15);
                    float val = acc[i][j][r];
                    if (MODE == 1) {
                        float g = bf2f(*(const unsigned short*)(Gin + rbase + col));
                        val = (g / (1.f + expf(-g))) * val;
                    }
                    *(unsigned short*)(Cout + rbase + col) = f2bf(val);
                }
            }
        }
    }
}

// ---------------------------------------------------------------- combine (Y bf16)
__global__ __launch_bounds__(256) void combine_kernel(const bf16* __restrict__ Y,
                                                      const int* __restrict__ slotrow,
                                                      const float* __restrict__ roww,
                                                      float* __restrict__ out) {
    int i = blockIdx.x * 256 + threadIdx.x;   // T * (D/8)
    if (i >= TT * (DD / 8)) return;
    int t = i >> 8;        // D/8 = 256
    int d8 = (i & 255) * 8;
    int r0 = slotrow[2 * t], r1 = slotrow[2 * t + 1];
    float w0 = roww[r0], w1 = roww[r1];
    uint4 ya = *(const uint4*)(Y + (size_t)r0 * DD + d8);
    uint4 yb = *(const uint4*)(Y + (size_t)r1 * DD + d8);
    const unsigned* pa = &ya.x;
    const unsigned* pb = &yb.x;
    float res[8];
#pragma unroll
    for (int k = 0; k < 4; k++) {
        float a0 = __uint_as_float(pa[k] << 16);
        float a1 = __uint_as_float(pa[k] & 0xffff0000u);
        float b0 = __uint_as_float(pb[k] << 16);
        float b1 = __uint_as_float(pb[k] & 0xffff0000u);
        res[2 * k]     = w0 * a0 + w1 * b0;
        res[2 * k + 1] = w0 * a1 + w1 * b1;
    }
    float* op = out + (size_t)t * DD + d8;
    *(float4*)op = make_float4(res[0], res[1], res[2], res[3]);
    *(float4*)(op + 4) = make_float4(res[4], res[5], res[6], res[7]);
}

// ---------------------------------------------------------------- launch
extern "C" void kernel_launch(void* const* d_in, const int* in_sizes, int n_in,
                              void* d_out, int out_size, void* d_ws, size_t ws_size,
                              hipStream_t stream) {
    const float* hidden  = (const float*)d_in[0];
    const float* cosb    = (const float*)d_in[1];
    const float* sinb    = (const float*)d_in[2];
    const float* ln1w    = (const float*)d_in[3];
    const float* ln2w    = (const float*)d_in[4];
    const float* wqkv    = (const float*)d_in[5];
    const float* wout    = (const float*)d_in[6];
    const float* wrouter = (const float*)d_in[7];
    const float* wgate   = (const float*)d_in[8];
    const float* wup     = (const float*)d_in[9];
    const float* wdown   = (const float*)d_in[10];

    float* outbuf   = (float*)d_out;
    float* out_moe  = outbuf;
    float* residual = outbuf + (size_t)TT * DD;

    float* ws   = (float*)d_ws;
    float* h    = ws;                                   // T*D f32
    float* qkv  = h + (size_t)TT * DD;                  // T*OQ f32
    float* attn = qkv + (size_t)TT * OQ;                // T*D f32
    bf16*  Xg   = (bf16*)(attn + (size_t)TT * DD);      // MOE_PAD*D bf16
    bf16*  gbuf = Xg + (size_t)MOE_PAD * DD;            // MOE_PAD*F bf16
    bf16*  Pbuf = gbuf + (size_t)MOE_PAD * FF;          // MOE_PAD*F bf16
    bf16*  Ybuf = Pbuf + (size_t)MOE_PAD * FF;          // MOE_PAD*D bf16
    int*   ip   = (int*)(Ybuf + (size_t)MOE_PAD * DD);
    int* counts  = ip;
    int* cursors = ip + 8;
    int* offsets = ip + 16;
    int* tok_e   = ip + 24;
    int* rowtok  = tok_e + 4096;
    int* slotrow = rowtok + 4096;
    float* tok_w = (float*)(slotrow + 4096);
    float* roww  = tok_w + 4096;

    hipMemsetAsync(counts, 0, 16 * sizeof(int), stream);

    ln_kernel<<<TT, 256, 0, stream>>>(hidden, ln1w, h);
    gemm_nt<<<dim3(OQ / 64, TT / 64), 256, 0, stream>>>(h, wqkv, nullptr, qkv, OQ, DD);
    rope_kernel<<<(TT * 20 * 64) / 256, 256, 0, stream>>>(qkv, cosb, sinb);
    fattn_kernel<<<dim3(64, 8), 256, 0, stream>>>(qkv, attn);
    gemm_nt<<<dim3(DD / 64, TT / 64), 256, 0, stream>>>(attn, wout, hidden, residual, DD, DD);
    ln_kernel<<<TT, 256, 0, stream>>>(residual, ln2w, h);
    router_kernel<<<TT, 256, 0, stream>>>(h, wrouter, tok_e, tok_w, counts);
    offsets_kernel<<<1, 64, 0, stream>>>(counts, offsets);
    assign_kernel<<<TT / 256, 256, 0, stream>>>(tok_e, tok_w, offsets, cursors, rowtok, roww, slotrow);
    gather_kernel<<<MOE_ROWS, 256, 0, stream>>>(h, rowtok, Xg);
    moe_mfma<0><<<dim3(FF / 128, MOE_ROWS / 128, NE), 256, 0, stream>>>(Xg, wgate, gbuf, nullptr, offsets, counts);
    moe_mfma<1><<<dim3(FF / 128, MOE_ROWS / 128, NE), 256, 0, stream>>>(Xg, wup, Pbuf, gbuf, offsets, counts);
    moe_mfma<2><<<dim3(DD / 128, MOE_ROWS / 128, NE), 256, 0, stream>>>(Pbuf, wdown, Ybuf, nullptr, offsets, counts);
    combine_kernel<<<(TT * (DD / 8)) / 256, 256, 0, stream>>>(Ybuf, slotrow, roww, out_moe);
}